// Round 4
// baseline (920.152 us; speedup 1.0000x reference)
//
#include <hip/hip_runtime.h>
#include <math.h>

#define EMBED 1024
#define NHEADS 16
#define HDIM 64
#define SEQ 2048
#define BATCH 2
#define BS (BATCH*SEQ)   // 4096

// Swizzled flat index for [64][64] LDS tiles stored as (k, r) with XOR on r:
// element (k, r) lives at k*64 + (r ^ ((k&7)<<2)). Keeps float4 reads (r = 4t)
// contiguous+aligned while spreading banks across k.
#define SWZ(k, r) (((k) << 6) + ((r) ^ (((k) & 7) << 2)))

// ---------------------------------------------------------------------------
// C[M,N] = A[M,K] @ W[K,N] + bias, all row-major fp32.
// 64x64 tile, BK=32, 256 threads, 4x4 micro-tile.
// ---------------------------------------------------------------------------
__global__ __launch_bounds__(256) void gemm_bias_kernel(
    const float* __restrict__ A, const float* __restrict__ W,
    const float* __restrict__ bias, float* __restrict__ C,
    int M, int N, int K)
{
    __shared__ float AsT[32][68];   // AsT[k][row], padded for banks
    __shared__ float Ws[32][64];    // Ws[k][col]

    const int tid = threadIdx.x;
    const int tx = tid & 15;        // 0..15 col group
    const int ty = tid >> 4;        // 0..15 row group
    const int rowBase = blockIdx.y * 64;
    const int colBase = blockIdx.x * 64;

    const int lr = tid >> 2;          // 0..63 A row
    const int lk = (tid & 3) * 8;     // 0,8,16,24 A k-offset (2 float4s)
    const int wr = tid >> 4;          // 0..15 W k-row (+16 for second)
    const int wc = (tid & 15) * 4;    // W col offset

    float acc[4][4] = {};

    for (int kk = 0; kk < K; kk += 32) {
        float4 a0 = *reinterpret_cast<const float4*>(&A[(size_t)(rowBase + lr) * K + kk + lk]);
        float4 a1 = *reinterpret_cast<const float4*>(&A[(size_t)(rowBase + lr) * K + kk + lk + 4]);
        float4 w0 = *reinterpret_cast<const float4*>(&W[(size_t)(kk + wr) * N + colBase + wc]);
        float4 w1 = *reinterpret_cast<const float4*>(&W[(size_t)(kk + wr + 16) * N + colBase + wc]);
        __syncthreads();
        AsT[lk+0][lr] = a0.x; AsT[lk+1][lr] = a0.y; AsT[lk+2][lr] = a0.z; AsT[lk+3][lr] = a0.w;
        AsT[lk+4][lr] = a1.x; AsT[lk+5][lr] = a1.y; AsT[lk+6][lr] = a1.z; AsT[lk+7][lr] = a1.w;
        *reinterpret_cast<float4*>(&Ws[wr][wc])      = w0;
        *reinterpret_cast<float4*>(&Ws[wr + 16][wc]) = w1;
        __syncthreads();

        #pragma unroll
        for (int k = 0; k < 32; ++k) {
            float4 a = *reinterpret_cast<const float4*>(&AsT[k][ty * 4]);
            float4 b = *reinterpret_cast<const float4*>(&Ws[k][tx * 4]);
            const float av[4] = {a.x, a.y, a.z, a.w};
            const float bv[4] = {b.x, b.y, b.z, b.w};
            #pragma unroll
            for (int i = 0; i < 4; ++i)
                #pragma unroll
                for (int j = 0; j < 4; ++j)
                    acc[i][j] = fmaf(av[i], bv[j], acc[i][j]);
        }
    }

    #pragma unroll
    for (int i = 0; i < 4; ++i) {
        const size_t r = (size_t)(rowBase + ty * 4 + i);
        const int c = colBase + tx * 4;
        float4 o;
        o.x = acc[i][0] + bias[c + 0];
        o.y = acc[i][1] + bias[c + 1];
        o.z = acc[i][2] + bias[c + 2];
        o.w = acc[i][3] + bias[c + 3];
        *reinterpret_cast<float4*>(&C[r * N + c]) = o;
    }
}

// ---------------------------------------------------------------------------
// MQA flash attention, fp32. One block = one (b, h, 64-row q-tile).
// K/V shared across heads. Online softmax fully in registers via shuffles.
// LDS: QsT/KsT/PsT swizzled [64][64] + Vs [64][64] = exactly 64 KiB.
// ---------------------------------------------------------------------------
__global__ __launch_bounds__(256) void mqa_attn_kernel(
    const float* __restrict__ Q, const float* __restrict__ Kb,
    const float* __restrict__ Vb, float* __restrict__ O)
{
    __shared__ float QsT[64 * 64];  // (k=headdim, r=qrow), swizzled, pre-scaled
    __shared__ float KsT[64 * 64];  // (k=headdim, r=key),  swizzled
    __shared__ float PsT[64 * 64];  // (k=key,     r=qrow), swizzled (holds P)
    __shared__ float Vs [64 * 64];  // (key, col), natural row-major

    const int tid = threadIdx.x;
    const int tx = tid & 15;     // 0..15 : col group (keys in QK, out-dim in PV)
    const int ty = tid >> 4;     // 0..15 : q-row group
    const int bid = blockIdx.x;
    const int qt = bid & 31;            // 32 q-tiles
    const int h  = (bid >> 5) & 15;     // 16 heads
    const int b  = bid >> 9;            // 2 batches
    const int q0 = qt * 64;

    const int lr = tid >> 2;            // 0..63 load row
    const int lc = (tid & 3) * 16;      // 0,16,32,48 load col base

    // ---- load Q tile transposed + scaled by 1/sqrt(D) = 1/32 ----
    {
        const float* src = &Q[((size_t)(b * SEQ + q0 + lr)) * EMBED + h * HDIM + lc];
        #pragma unroll
        for (int u = 0; u < 16; u += 4) {
            float4 t = *reinterpret_cast<const float4*>(src + u);
            QsT[SWZ(lc + u + 0, lr)] = t.x * 0.03125f;
            QsT[SWZ(lc + u + 1, lr)] = t.y * 0.03125f;
            QsT[SWZ(lc + u + 2, lr)] = t.z * 0.03125f;
            QsT[SWZ(lc + u + 3, lr)] = t.w * 0.03125f;
        }
    }

    float acc[4][4] = {};
    float mreg[4], lreg[4];
    #pragma unroll
    for (int i = 0; i < 4; ++i) { mreg[i] = -3.402823466e+38f; lreg[i] = 0.0f; }

    for (int kt = 0; kt < SEQ / 64; ++kt) {
        const int k0 = kt * 64;
        // prefetch K/V tile rows into registers (before barrier)
        const float* ksrc = &Kb[((size_t)(b * SEQ + k0 + lr)) * HDIM + lc];
        const float* vsrc = &Vb[((size_t)(b * SEQ + k0 + lr)) * HDIM + lc];
        float4 kr[4], vr[4];
        #pragma unroll
        for (int u = 0; u < 4; ++u) {
            kr[u] = *reinterpret_cast<const float4*>(ksrc + 4 * u);
            vr[u] = *reinterpret_cast<const float4*>(vsrc + 4 * u);
        }
        __syncthreads();   // prior tile fully consumed (also guards Q writes, iter 0)
        #pragma unroll
        for (int u = 0; u < 4; ++u) {
            KsT[SWZ(lc + 4*u + 0, lr)] = kr[u].x;
            KsT[SWZ(lc + 4*u + 1, lr)] = kr[u].y;
            KsT[SWZ(lc + 4*u + 2, lr)] = kr[u].z;
            KsT[SWZ(lc + 4*u + 3, lr)] = kr[u].w;
            *reinterpret_cast<float4*>(&Vs[lr * 64 + lc + 4*u]) = vr[u];
        }
        __syncthreads();

        // ---- S-tile = (Q/32) K^T : rows 4ty+i, keys 4tx+j ----
        float sacc[4][4] = {};
        #pragma unroll 8
        for (int k = 0; k < 64; ++k) {
            float4 a = *reinterpret_cast<const float4*>(&QsT[(k << 6) + ((ty * 4) ^ ((k & 7) << 2))]);
            float4 bb = *reinterpret_cast<const float4*>(&KsT[(k << 6) + ((tx * 4) ^ ((k & 7) << 2))]);
            const float av[4] = {a.x, a.y, a.z, a.w};
            const float bv[4] = {bb.x, bb.y, bb.z, bb.w};
            #pragma unroll
            for (int i = 0; i < 4; ++i)
                #pragma unroll
                for (int j = 0; j < 4; ++j)
                    sacc[i][j] = fmaf(av[i], bv[j], sacc[i][j]);
        }

        // ---- online softmax, fully in registers (16-lane row groups) ----
        #pragma unroll
        for (int i = 0; i < 4; ++i) {
            float m = fmaxf(fmaxf(sacc[i][0], sacc[i][1]), fmaxf(sacc[i][2], sacc[i][3]));
            m = fmaxf(m, __shfl_xor(m, 1));
            m = fmaxf(m, __shfl_xor(m, 2));
            m = fmaxf(m, __shfl_xor(m, 4));
            m = fmaxf(m, __shfl_xor(m, 8));
            const float mn = fmaxf(mreg[i], m);
            const float al = __expf(mreg[i] - mn);
            mreg[i] = mn;
            float rs = 0.0f;
            #pragma unroll
            for (int j = 0; j < 4; ++j) {
                const float p = __expf(sacc[i][j] - mn);
                PsT[SWZ(tx * 4 + j, ty * 4 + i)] = p;   // (key, qrow)
                rs += p;
                acc[i][j] *= al;
            }
            rs += __shfl_xor(rs, 1);
            rs += __shfl_xor(rs, 2);
            rs += __shfl_xor(rs, 4);
            rs += __shfl_xor(rs, 8);
            lreg[i] = lreg[i] * al + rs;
        }
        __syncthreads();   // P visible to all

        // ---- O += P @ V : rows 4ty+i, out-cols 4tx+j, reduce over keys ----
        #pragma unroll 8
        for (int k = 0; k < 64; ++k) {
            float4 a = *reinterpret_cast<const float4*>(&PsT[(k << 6) + ((ty * 4) ^ ((k & 7) << 2))]);
            float4 bb = *reinterpret_cast<const float4*>(&Vs[k * 64 + tx * 4]);
            const float av[4] = {a.x, a.y, a.z, a.w};
            const float bv[4] = {bb.x, bb.y, bb.z, bb.w};
            #pragma unroll
            for (int i = 0; i < 4; ++i)
                #pragma unroll
                for (int j = 0; j < 4; ++j)
                    acc[i][j] = fmaf(av[i], bv[j], acc[i][j]);
        }
    }

    // ---- epilogue: divide by row sums, write [b, q, h, hd] (= [B,S,D]) ----
    #pragma unroll
    for (int i = 0; i < 4; ++i) {
        const float linv = 1.0f / lreg[i];
        float4 o;
        o.x = acc[i][0] * linv;
        o.y = acc[i][1] * linv;
        o.z = acc[i][2] * linv;
        o.w = acc[i][3] * linv;
        *reinterpret_cast<float4*>(
            &O[((size_t)(b * SEQ + q0 + ty * 4 + i)) * EMBED + h * HDIM + tx * 4]) = o;
    }
}

// ---------------------------------------------------------------------------
extern "C" void kernel_launch(void* const* d_in, const int* in_sizes, int n_in,
                              void* d_out, int out_size, void* d_ws, size_t ws_size,
                              hipStream_t stream) {
    const float* x  = (const float*)d_in[0];
    const float* wq = (const float*)d_in[1];
    const float* bq = (const float*)d_in[2];
    const float* wk = (const float*)d_in[3];
    const float* bk = (const float*)d_in[4];
    const float* wv = (const float*)d_in[5];
    const float* wv_b = (const float*)d_in[6];
    const float* wo = (const float*)d_in[7];
    const float* bo = (const float*)d_in[8];
    float* out = (float*)d_out;

    // Scratch layout. Q is staged in d_out (same size as final output) so ws
    // only needs k + v + attn_out = (2*4096*64 + 4096*1024)*4 B ≈ 18.9 MB.
    float* qbuf = (float*)d_out;
    float* ws   = (float*)d_ws;
    float* kbuf = ws;                              // [BS, 64]
    float* vbuf = kbuf + (size_t)BS * HDIM;        // [BS, 64]
    float* abuf = vbuf + (size_t)BS * HDIM;        // [BS, 1024]

    // Q = x @ wq + bq   -> qbuf (d_out)
    gemm_bias_kernel<<<dim3(EMBED / 64, BS / 64), 256, 0, stream>>>(
        x, wq, bq, qbuf, BS, EMBED, EMBED);
    // K = x @ wk + bk, V = x @ wv + bv
    gemm_bias_kernel<<<dim3(1, BS / 64), 256, 0, stream>>>(
        x, wk, bk, kbuf, BS, HDIM, EMBED);
    gemm_bias_kernel<<<dim3(1, BS / 64), 256, 0, stream>>>(
        x, wv, wv_b, vbuf, BS, HDIM, EMBED);
    // attention -> abuf
    mqa_attn_kernel<<<BATCH * NHEADS * (SEQ / 64), 256, 0, stream>>>(
        qbuf, kbuf, vbuf, abuf);
    // out = abuf @ wo + bo
    gemm_bias_kernel<<<dim3(EMBED / 64, BS / 64), 256, 0, stream>>>(
        abuf, wo, bo, out, BS, EMBED, EMBED);
}

// Round 7
// 348.096 us; speedup vs baseline: 2.6434x; 2.6434x over previous
//
#include <hip/hip_runtime.h>

typedef unsigned short ushort_t;
typedef __attribute__((ext_vector_type(8))) short short8;
typedef __attribute__((ext_vector_type(4))) float f32x4;

#define EMBED 1024
#define NHEADS 16
#define HDIM 64
#define SEQ 2048
#define BATCH 2
#define BS (BATCH*SEQ)              // 4096
#define QSCALE 0.045084234f         // log2(e)/sqrt(1024): fold softmax scale + exp2 conversion into Q

// round-to-nearest-even fp32 -> bf16
static __device__ __forceinline__ ushort_t f2b(float x) {
    union { float f; unsigned u; } v; v.f = x;
    unsigned r = v.u + 0x7FFFu + ((v.u >> 16) & 1u);
    return (ushort_t)(r >> 16);
}

// ---------------------------------------------------------------------------
// Transpose-cast: src fp32 [K][N] row-major  ->  dst bf16 [N][K] row-major.
// Thread handles 4 consecutive k's of one n. Reads coalesced over n.
// ---------------------------------------------------------------------------
__global__ __launch_bounds__(256) void tcast_kernel(
    const float* __restrict__ src, ushort_t* __restrict__ dst,
    int N, int nshift, int K, int total4)
{
    int t = blockIdx.x * 256 + threadIdx.x;
    if (t >= total4) return;
    int n = t & (N - 1);
    int k0 = (t >> nshift) << 2;
    ushort4 o;
    o.x = f2b(src[(size_t)(k0 + 0) * N + n]);
    o.y = f2b(src[(size_t)(k0 + 1) * N + n]);
    o.z = f2b(src[(size_t)(k0 + 2) * N + n]);
    o.w = f2b(src[(size_t)(k0 + 3) * N + n]);
    *reinterpret_cast<ushort4*>(dst + (size_t)n * K + k0) = o;
}

// ---------------------------------------------------------------------------
// MFMA GEMM: C[M=4096, N=128*gridX] = A[4096,1024] @ Bt^T + bias.
//   A: fp32 [4096][1024] (MODE 0/1, cast to bf16 while staging) or
//      bf16 [4096][1024] (MODE 2).
//   Bt: bf16 [N][1024]  (pre-transposed weights).
// 128x128 block tile, 4 waves (2x2), each wave 64x64 = 4x4 mfma tiles, BK=32.
// LDS tiles [128 rows][32 k] bf16, 64B rows, 2-bit XOR swizzle on 16B chunks.
// MODE 0: Q-proj  -> bf16 out, (acc+bias)*QSCALE
// MODE 1: KV-proj -> cols 0-63: k_bf16 [4096][64] (+bk); cols 64-127:
//                    vt bf16 [b][64][2048] transposed scatter (+bv)
// MODE 2: O-proj  -> fp32 out (+bo)
// ---------------------------------------------------------------------------
template<int MODE>
__global__ __launch_bounds__(256) void mfma_gemm(
    const float* __restrict__ Af, const ushort_t* __restrict__ Ab,
    const ushort_t* __restrict__ Bt,
    const float* __restrict__ bias0, const float* __restrict__ bias1,
    float* __restrict__ Of, ushort_t* __restrict__ Ob, ushort_t* __restrict__ Ovt)
{
    __shared__ ushort_t As[128 * 32];
    __shared__ ushort_t Bs[128 * 32];

    const int tid = threadIdx.x;
    const int lane = tid & 63;
    const int w = tid >> 6;
    const int g = lane >> 4;        // 0..3
    const int c = lane & 15;        // 0..15
    const int wy = w >> 1, wx = w & 1;
    const int rowBase = blockIdx.y * 128;
    const int colBase = blockIdx.x * 128;

    f32x4 acc[4][4];
    #pragma unroll
    for (int i = 0; i < 4; ++i)
        #pragma unroll
        for (int j = 0; j < 4; ++j)
            acc[i][j] = (f32x4){0.f, 0.f, 0.f, 0.f};

    for (int kk = 0; kk < 1024; kk += 32) {
        __syncthreads();   // prior tile fully consumed
        // ---- stage A tile (128x32 bf16) ----
        if (MODE != 2) {
            #pragma unroll
            for (int u = 0; u < 2; ++u) {
                const int o = tid * 32 + u * 16;        // byte offset in 8KB tile
                const int row = o >> 6, kb = o & 63;
                const float* s = Af + (size_t)(rowBase + row) * 1024 + kk + (kb >> 1);
                float4 f0 = *reinterpret_cast<const float4*>(s);
                float4 f1 = *reinterpret_cast<const float4*>(s + 4);
                short8 h;
                h[0] = (short)f2b(f0.x); h[1] = (short)f2b(f0.y);
                h[2] = (short)f2b(f0.z); h[3] = (short)f2b(f0.w);
                h[4] = (short)f2b(f1.x); h[5] = (short)f2b(f1.y);
                h[6] = (short)f2b(f1.z); h[7] = (short)f2b(f1.w);
                *reinterpret_cast<short8*>((char*)As + (o ^ ((row & 3) << 4))) = h;
            }
        } else {
            #pragma unroll
            for (int u = 0; u < 2; ++u) {
                const int o = u * 4096 + tid * 16;
                const int row = o >> 6, kb = o & 63;
                const ushort_t* s = Ab + (size_t)(rowBase + row) * 1024 + kk + (kb >> 1);
                *reinterpret_cast<short8*>((char*)As + (o ^ ((row & 3) << 4))) =
                    *reinterpret_cast<const short8*>(s);
            }
        }
        // ---- stage B tile (Bt rows = output cols) ----
        #pragma unroll
        for (int u = 0; u < 2; ++u) {
            const int o = u * 4096 + tid * 16;
            const int row = o >> 6, kb = o & 63;
            const ushort_t* s = Bt + (size_t)(colBase + row) * 1024 + kk + (kb >> 1);
            *reinterpret_cast<short8*>((char*)Bs + (o ^ ((row & 3) << 4))) =
                *reinterpret_cast<const short8*>(s);
        }
        __syncthreads();

        short8 af[4], bf[4];
        #pragma unroll
        for (int mt = 0; mt < 4; ++mt) {
            const int row = wy * 64 + mt * 16 + c;
            af[mt] = *reinterpret_cast<const short8*>(
                (const char*)As + row * 64 + ((g * 16) ^ ((row & 3) << 4)));
        }
        #pragma unroll
        for (int nt = 0; nt < 4; ++nt) {
            const int row = wx * 64 + nt * 16 + c;
            bf[nt] = *reinterpret_cast<const short8*>(
                (const char*)Bs + row * 64 + ((g * 16) ^ ((row & 3) << 4)));
        }
        #pragma unroll
        for (int mt = 0; mt < 4; ++mt)
            #pragma unroll
            for (int nt = 0; nt < 4; ++nt)
                acc[mt][nt] = __builtin_amdgcn_mfma_f32_16x16x32_bf16(
                    af[mt], bf[nt], acc[mt][nt], 0, 0, 0);
    }

    // ---- epilogue ----
    #pragma unroll
    for (int nt = 0; nt < 4; ++nt) {
        const int colAbs = colBase + wx * 64 + nt * 16 + c;
        float bv0;
        if (MODE == 1) bv0 = (colAbs < 64) ? bias0[colAbs] : bias1[colAbs - 64];
        else           bv0 = bias0[colAbs];
        #pragma unroll
        for (int mt = 0; mt < 4; ++mt) {
            const int rowA = rowBase + wy * 64 + mt * 16 + g * 4;
            #pragma unroll
            for (int r = 0; r < 4; ++r) {
                const float v = acc[mt][nt][r] + bv0;
                const int row = rowA + r;
                if (MODE == 0) {
                    Ob[(size_t)row * 1024 + colAbs] = f2b(v * QSCALE);
                } else if (MODE == 2) {
                    Of[(size_t)row * 1024 + colAbs] = v;
                } else {
                    if (colAbs < 64)
                        Ob[(size_t)row * 64 + colAbs] = f2b(v);
                    else
                        Ovt[((size_t)(row >> 11) * 64 + (colAbs - 64)) * 2048 + (row & 2047)] = f2b(v);
                }
            }
        }
    }
}

// ---------------------------------------------------------------------------
// MFMA MQA flash attention. Block = (b, h, 64 q-rows), 4 waves; each wave owns
// 16 q-rows, fully independent (NO barriers in the k-loop).
// Computes S^T = K.Q^T so each lane owns ONE q-row (col of D): softmax needs
// only shfl_xor 16/32. P is transposed per-wave via a private swizzled LDS
// tile into PV's B-operand layout. PV computes out^T = V^T.P^T with V^T
// fragments loaded straight from the pre-transposed vt[b][hd][s] buffer.
// q is pre-scaled by log2(e)/sqrt(D) so softmax uses exp2 directly.
// ---------------------------------------------------------------------------
__global__ __launch_bounds__(256) void attn_mfma_kernel(
    const ushort_t* __restrict__ q,   // [4096][1024] bf16, scaled
    const ushort_t* __restrict__ kb,  // [4096][64]   bf16
    const ushort_t* __restrict__ vt,  // [2][64][2048] bf16
    ushort_t* __restrict__ aout)      // [4096][1024] bf16
{
    __shared__ char P_lds[4 * 2048];  // per-wave 16 rows x 64 keys bf16 (128B rows)

    const int tid = threadIdx.x;
    const int lane = tid & 63;
    const int w = tid >> 6;
    const int g = lane >> 4;          // 0..3
    const int c = lane & 15;          // q-row within wave (owns this row!)
    const int bid = blockIdx.x;
    const int qt = bid & 31;
    const int h = (bid >> 5) & 15;
    const int b = bid >> 9;
    const int q0 = qt * 64;

    char* pl = P_lds + w * 2048;
    // swizzled byte offset in a [16][128B] tile: row*128 + (kb ^ ((row&7)<<4))
    #define PSWZ(row, kbyte) ((row) * 128 + ((kbyte) ^ (((row) & 7) << 4)))

    // ---- Q^T B-fragments: lane holds Q[q0+w*16+c][ks*32+g*8+j], loaded once ----
    short8 bq[2];
    {
        const size_t qrow = (size_t)(b * SEQ + q0 + w * 16 + c) * 1024 + h * 64;
        bq[0] = *reinterpret_cast<const short8*>(q + qrow + 0 * 32 + g * 8);
        bq[1] = *reinterpret_cast<const short8*>(q + qrow + 1 * 32 + g * 8);
    }

    f32x4 oacc[4];
    #pragma unroll
    for (int i = 0; i < 4; ++i) oacc[i] = (f32x4){0.f, 0.f, 0.f, 0.f};
    float m_run = -1e30f, l_run = 0.f;

    for (int kt = 0; kt < SEQ / 64; ++kt) {
        // ---- load K A-frags and V^T A-frags (global, L2/L3-resident) ----
        short8 ak[4][2], av[4][2];
        #pragma unroll
        for (int mt = 0; mt < 4; ++mt) {
            const size_t krow = (size_t)(b * SEQ + kt * 64 + mt * 16 + c) * 64;
            ak[mt][0] = *reinterpret_cast<const short8*>(kb + krow + 0 * 32 + g * 8);
            ak[mt][1] = *reinterpret_cast<const short8*>(kb + krow + 1 * 32 + g * 8);
            const size_t vrow = ((size_t)(b * 64) + mt * 16 + c) * 2048 + kt * 64;
            av[mt][0] = *reinterpret_cast<const short8*>(vt + vrow + 0 * 32 + g * 8);
            av[mt][1] = *reinterpret_cast<const short8*>(vt + vrow + 1 * 32 + g * 8);
        }

        // ---- S^T tile: D[key=mt*16+g*4+reg][qrow=c] ----
        f32x4 sacc[4];
        #pragma unroll
        for (int mt = 0; mt < 4; ++mt) {
            sacc[mt] = (f32x4){0.f, 0.f, 0.f, 0.f};
            sacc[mt] = __builtin_amdgcn_mfma_f32_16x16x32_bf16(ak[mt][0], bq[0], sacc[mt], 0, 0, 0);
            sacc[mt] = __builtin_amdgcn_mfma_f32_16x16x32_bf16(ak[mt][1], bq[1], sacc[mt], 0, 0, 0);
        }

        // ---- online softmax over the lane's row (64 keys: 16 local + shfl) ----
        float pmax = sacc[0][0];
        #pragma unroll
        for (int mt = 0; mt < 4; ++mt)
            #pragma unroll
            for (int r = 0; r < 4; ++r)
                pmax = fmaxf(pmax, sacc[mt][r]);
        pmax = fmaxf(pmax, __shfl_xor(pmax, 16));
        pmax = fmaxf(pmax, __shfl_xor(pmax, 32));
        const float mn = fmaxf(m_run, pmax);
        const float al = exp2f(m_run - mn);
        m_run = mn;

        float rs = 0.f;
        #pragma unroll
        for (int mt = 0; mt < 4; ++mt) {
            const float p0 = exp2f(sacc[mt][0] - mn);
            const float p1 = exp2f(sacc[mt][1] - mn);
            const float p2 = exp2f(sacc[mt][2] - mn);
            const float p3 = exp2f(sacc[mt][3] - mn);
            rs += (p0 + p1) + (p2 + p3);
            uint2 pk;
            pk.x = (unsigned)f2b(p0) | ((unsigned)f2b(p1) << 16);
            pk.y = (unsigned)f2b(p2) | ((unsigned)f2b(p3) << 16);
            *reinterpret_cast<uint2*>(pl + PSWZ(c, mt * 32 + g * 8)) = pk;
        }
        rs += __shfl_xor(rs, 16);
        rs += __shfl_xor(rs, 32);
        l_run = l_run * al + rs;
        #pragma unroll
        for (int mt = 0; mt < 4; ++mt)
            #pragma unroll
            for (int r = 0; r < 4; ++r)
                oacc[mt][r] *= al;

        asm volatile("s_waitcnt lgkmcnt(0)" ::: "memory");

        // ---- out^T += V^T . P^T ----
        #pragma unroll
        for (int ks = 0; ks < 2; ++ks) {
            short8 pf = *reinterpret_cast<const short8*>(
                pl + PSWZ(c, ks * 64 + g * 16));
            #pragma unroll
            for (int mt = 0; mt < 4; ++mt)
                oacc[mt] = __builtin_amdgcn_mfma_f32_16x16x32_bf16(av[mt][ks], pf, oacc[mt], 0, 0, 0);
        }
    }

    // ---- epilogue: out^T -> LDS transpose -> coalesced bf16 store ----
    const float linv = 1.0f / l_run;
    #pragma unroll
    for (int mt = 0; mt < 4; ++mt) {
        uint2 ok;
        ok.x = (unsigned)f2b(oacc[mt][0] * linv) | ((unsigned)f2b(oacc[mt][1] * linv) << 16);
        ok.y = (unsigned)f2b(oacc[mt][2] * linv) | ((unsigned)f2b(oacc[mt][3] * linv) << 16);
        *reinterpret_cast<uint2*>(pl + PSWZ(c, mt * 32 + g * 8)) = ok;
    }
    asm volatile("s_waitcnt lgkmcnt(0)" ::: "memory");
    {
        const int qr = lane >> 2, ch = lane & 3;
        uint4 d0 = *reinterpret_cast<const uint4*>(pl + PSWZ(qr, ch * 32));
        uint4 d1 = *reinterpret_cast<const uint4*>(pl + PSWZ(qr, ch * 32 + 16));
        ushort_t* dst = aout + (size_t)(b * SEQ + q0 + w * 16 + qr) * 1024 + h * 64 + ch * 16;
        *reinterpret_cast<uint4*>(dst) = d0;
        *reinterpret_cast<uint4*>(dst + 8) = d1;
    }
    #undef PSWZ
}

// ---------------------------------------------------------------------------
extern "C" void kernel_launch(void* const* d_in, const int* in_sizes, int n_in,
                              void* d_out, int out_size, void* d_ws, size_t ws_size,
                              hipStream_t stream) {
    const float* x  = (const float*)d_in[0];
    const float* wq = (const float*)d_in[1];
    const float* bq = (const float*)d_in[2];
    const float* wk = (const float*)d_in[3];
    const float* bk = (const float*)d_in[4];
    const float* wv = (const float*)d_in[5];
    const float* bv = (const float*)d_in[6];
    const float* wo = (const float*)d_in[7];
    const float* bo = (const float*)d_in[8];
    float* out = (float*)d_out;

    // ws layout (bf16 elements). Total 13.25 MB (< proven-safe 18.9 MB).
    ushort_t* ws    = (ushort_t*)d_ws;
    ushort_t* wq_t  = ws;                        // [1024][1024]
    ushort_t* wo_t  = wq_t + 1024 * 1024;        // [1024][1024]
    ushort_t* wkv_t = wo_t + 1024 * 1024;        // [128][1024] (wk rows 0-63, wv rows 64-127)
    ushort_t* kbuf  = wkv_t + 128 * 1024;        // [4096][64]
    ushort_t* vtb   = kbuf + (size_t)BS * 64;    // [2][64][2048]
    ushort_t* abuf  = vtb + (size_t)BS * 64;     // [4096][1024]
    ushort_t* qbuf  = (ushort_t*)d_out;          // [4096][1024] staged in d_out (8MB <= 16MB)

    // ---- transpose-cast weights to bf16 [N][K] ----
    tcast_kernel<<<1024, 256, 0, stream>>>(wq, wq_t, 1024, 10, 1024, 1024 * 256);
    tcast_kernel<<<1024, 256, 0, stream>>>(wo, wo_t, 1024, 10, 1024, 1024 * 256);
    tcast_kernel<<<64, 256, 0, stream>>>(wk, wkv_t,            64, 6, 1024, 64 * 256);
    tcast_kernel<<<64, 256, 0, stream>>>(wv, wkv_t + 64 * 1024, 64, 6, 1024, 64 * 256);

    // ---- projections ----
    mfma_gemm<0><<<dim3(8, 32), 256, 0, stream>>>(x, nullptr, wq_t, bq, nullptr,
                                                  nullptr, qbuf, nullptr);
    mfma_gemm<1><<<dim3(1, 32), 256, 0, stream>>>(x, nullptr, wkv_t, bk, bv,
                                                  nullptr, kbuf, vtb);
    // ---- attention ----
    attn_mfma_kernel<<<BATCH * NHEADS * (SEQ / 64), 256, 0, stream>>>(qbuf, kbuf, vtb, abuf);
    // ---- output projection (fp32 out) ----
    mfma_gemm<2><<<dim3(8, 32), 256, 0, stream>>>(nullptr, abuf, wo_t, bo, nullptr,
                                                  out, nullptr, nullptr);
}